// Round 2
// baseline (217.537 us; speedup 1.0000x reference)
//
#include <hip/hip_runtime.h>
#include <hip/hip_bf16.h>

// Problem constants
#define B_SZ   16384
#define D_SZ   768
#define H_SZ   128
#define S_SZ   65536
#define E_SZ   7

// Packed GEMM geometry (logical K/N spaces; B stored frag-major, see pack kernel)
// K layout: [0,768) h_t | [768,896) s_t | [896,1664) h_ctx | 1664..1666 sent | 1667 bias(1.0) | pad->1696
// N layout: [0,256) r,z (gi+gh summed) | [256,384) i_n | [384,512) h_n | [512,519) W_e | 519 W_s | pad->528
#define NFR    33      // N fragments of 16
#define NSTEP  53      // K steps of 32: 24 (h_t) + 4 (s_t) + 24 (h_ctx) + 1 (tail)

typedef __attribute__((ext_vector_type(8))) short bf16x8;
typedef __attribute__((ext_vector_type(4))) float f32x4;

static __device__ __forceinline__ ushort f2bf(float v) {
    unsigned u = __float_as_uint(v);
    u = (u + 0x7FFFu + ((u >> 16) & 1u)) >> 16;   // RNE
    return (ushort)u;
}

static __device__ __forceinline__ bf16x8 cvt8(float4 a, float4 b) {
    bf16x8 o;
    o[0] = (short)f2bf(a.x); o[1] = (short)f2bf(a.y);
    o[2] = (short)f2bf(a.z); o[3] = (short)f2bf(a.w);
    o[4] = (short)f2bf(b.x); o[5] = (short)f2bf(b.y);
    o[6] = (short)f2bf(b.z); o[7] = (short)f2bf(b.w);
    return o;
}

// logical packed-weight value at (n, k)
static __device__ __forceinline__ float w2_value(int n, int k,
    const float* __restrict__ W_ih, const float* __restrict__ W_hh,
    const float* __restrict__ b_ih, const float* __restrict__ b_hh,
    const float* __restrict__ W_e,  const float* __restrict__ b_e,
    const float* __restrict__ W_s,  const float* __restrict__ b_s)
{
    float v = 0.0f;
    if (n < 256) {                       // r,z rows: gi + gh summed
        if (k < 768)                        v = W_ih[(size_t)n * 771 + k];
        else if (k < 896)                   v = W_hh[(size_t)n * 128 + (k - 768)];
        else if (k >= 1664 && k < 1667)     v = W_ih[(size_t)n * 771 + 768 + (k - 1664)];
        else if (k == 1667)                 v = b_ih[n] + b_hh[n];
    } else if (n < 384) {                // i_n rows (W_ih rows 256..383)
        if (k < 768)                        v = W_ih[(size_t)n * 771 + k];
        else if (k >= 1664 && k < 1667)     v = W_ih[(size_t)n * 771 + 768 + (k - 1664)];
        else if (k == 1667)                 v = b_ih[n];
    } else if (n < 512) {                // h_n rows (W_hh rows 256..383)
        int g = n - 128;
        if (k >= 768 && k < 896)            v = W_hh[(size_t)g * 128 + (k - 768)];
        else if (k == 1667)                 v = b_hh[g];
    } else if (n < 520) {                // heads: z_t = [h_t(0:768) sent(768:771) s_t(771:899) h_ctx(899:1667)]
        int e = n - 512;
        const float* Wr = (e < E_SZ) ? (W_e + (size_t)e * 1667) : W_s;
        if (k < 768)                        v = Wr[k];
        else if (k < 896)                   v = Wr[771 + (k - 768)];
        else if (k < 1664)                  v = Wr[899 + (k - 896)];
        else if (k < 1667)                  v = Wr[768 + (k - 1664)];
        else if (k == 1667)                 v = (e < E_SZ) ? b_e[e] : b_s[0];
    }
    return v;
}

// ---------------- pack W2 frag-major: W2f[(nf*NSTEP + kstep)*64 + lane][8] ----------------
__global__ __launch_bounds__(256) void pack_w2f_kernel(
    const float* __restrict__ W_ih, const float* __restrict__ W_hh,
    const float* __restrict__ b_ih, const float* __restrict__ b_hh,
    const float* __restrict__ W_e,  const float* __restrict__ b_e,
    const float* __restrict__ W_s,  const float* __restrict__ b_s,
    ushort* __restrict__ W2f)
{
    int tid = blockIdx.x * 256 + threadIdx.x;
    if (tid >= NFR * NSTEP * 64) return;
    int lane  = tid & 63;
    int kstep = (tid >> 6) % NSTEP;
    int nf    = tid / (NSTEP * 64);
    int n     = nf * 16 + (lane & 15);
    int kbase = kstep * 32 + (lane >> 4) * 8;
    ushort o[8];
#pragma unroll
    for (int j = 0; j < 8; ++j)
        o[j] = f2bf(w2_value(n, kbase + j, W_ih, W_hh, b_ih, b_hh, W_e, b_e, W_s, b_s));
    *reinterpret_cast<uint4*>(W2f + (size_t)tid * 8) = *reinterpret_cast<const uint4*>(o);
}

// ---------------- winner (last-write-wins) ----------------
__global__ __launch_bounds__(256) void winner_kernel(const int* __restrict__ slot_ids,
                                                     int* __restrict__ winner)
{
    int b = blockIdx.x * 256 + threadIdx.x;
    if (b < B_SZ) atomicMax(&winner[slot_ids[b]], b);
}

// ---------------- per-step MFMA over compile-time frag ranges ----------------
template<int LO1, int HI1, int LO2, int HI2>
static __device__ __forceinline__ void mfma_step(const ushort* __restrict__ W2f,
                                                 int kstep, int lane, bf16x8 a, f32x4* acc)
{
#pragma unroll
    for (int nf = LO1; nf < HI1; ++nf) {
        bf16x8 b = *reinterpret_cast<const bf16x8*>(
            W2f + ((size_t)(nf * NSTEP + kstep) * 64 + lane) * 8);
        acc[nf] = __builtin_amdgcn_mfma_f32_16x16x32_bf16(a, b, acc[nf], 0, 0, 0);
    }
#pragma unroll
    for (int nf = LO2; nf < HI2; ++nf) {
        bf16x8 b = *reinterpret_cast<const bf16x8*>(
            W2f + ((size_t)(nf * NSTEP + kstep) * 64 + lane) * 8);
        acc[nf] = __builtin_amdgcn_mfma_f32_16x16x32_bf16(a, b, acc[nf], 0, 0, 0);
    }
}

// ---------------- fused GEMM + GRU + heads + scatter (no LDS, no barriers) ----------------
__global__ __launch_bounds__(256, 1) void fused_kernel(
    const float* __restrict__ h_t,   const float* __restrict__ h_ctx,
    const float* __restrict__ sent,  const int* __restrict__ slot_ids,
    const float* __restrict__ memory,const ushort* __restrict__ W2f,
    const int* __restrict__ winner,
    float* __restrict__ out_emo, float* __restrict__ out_shift, float* __restrict__ out_mem)
{
    const int tid  = threadIdx.x;
    const int wave = tid >> 6;
    const int lane = tid & 63;
    const int col  = lane & 15;
    const int kg   = lane >> 4;
    const int rowA = blockIdx.x * 64 + wave * 16 + col;   // A-fragment row for this lane
    const int slotA = slot_ids[rowA];

    // uniform-step A source address (lane's 8-float chunk)
    auto aptr = [&](int s) -> const float* {
        if (s < 24)      return h_t    + (size_t)rowA  * D_SZ + (s * 32 + kg * 8);
        else if (s < 28) return memory + (size_t)slotA * H_SZ + ((s - 24) * 32 + kg * 8);
        else             return h_ctx  + (size_t)rowA  * D_SZ + ((s - 28) * 32 + kg * 8);
    };

    f32x4 acc[NFR];
#pragma unroll
    for (int i = 0; i < NFR; ++i) { f32x4 z = {0.f, 0.f, 0.f, 0.f}; acc[i] = z; }

    float4 na0 = *reinterpret_cast<const float4*>(aptr(0));
    float4 na1 = *reinterpret_cast<const float4*>(aptr(0) + 4);

    // Phase 1: h_t (steps 0..23). Active frags: rz+i_n [0,24) + heads [32,33)
    for (int s = 0; s < 24; ++s) {
        bf16x8 a = cvt8(na0, na1);
        const float* p = aptr(s + 1);
        na0 = *reinterpret_cast<const float4*>(p);
        na1 = *reinterpret_cast<const float4*>(p + 4);
        mfma_step<0, 24, 32, 33>(W2f, s, lane, a, acc);
    }
    // Phase 2: s_t gather (steps 24..27). Active: rz [0,16) + h_n+heads [24,33)
    for (int s = 24; s < 28; ++s) {
        bf16x8 a = cvt8(na0, na1);
        const float* p = aptr(s + 1);
        na0 = *reinterpret_cast<const float4*>(p);
        na1 = *reinterpret_cast<const float4*>(p + 4);
        mfma_step<0, 16, 24, 33>(W2f, s, lane, a, acc);
    }
    // Phase 3: h_ctx (steps 28..51). Active: heads only [32,33)
    for (int s = 28; s < 52; ++s) {
        bf16x8 a = cvt8(na0, na1);
        if (s < 51) {
            const float* p = aptr(s + 1);
            na0 = *reinterpret_cast<const float4*>(p);
            na1 = *reinterpret_cast<const float4*>(p + 4);
        }
        mfma_step<32, 33, 33, 33>(W2f, s, lane, a, acc);
    }
    // Phase 4: tail (step 52): sent(3) + bias-one + zeros. Active: all frags
    {
        bf16x8 a;
#pragma unroll
        for (int j = 0; j < 8; ++j) {
            int kk = kg * 8 + j;
            float v = 0.0f;
            if (kk < 3)       v = sent[(size_t)rowA * 3 + kk];
            else if (kk == 3) v = 1.0f;
            a[j] = (short)f2bf(v);
        }
        mfma_step<0, 33, 33, 33>(W2f, 52, lane, a, acc);
    }

    // Epilogue: lane-local GRU + heads + winner-scatter.
    // D layout: col = lane&15, row = (lane>>4)*4 + reg
    const int rbase = wave * 16 + (lane >> 4) * 4;
#pragma unroll
    for (int r = 0; r < 4; ++r) {
        const int row  = blockIdx.x * 64 + rbase + r;
        const int slot = slot_ids[row];
        const bool win = (winner[slot] == row);
#pragma unroll
        for (int nf = 0; nf < 8; ++nf) {
            const int j = nf * 16 + col;               // hidden index 0..127
            float rg  = acc[nf][r];                    // r-gate preact (biased)
            float zg  = acc[8 + nf][r];                // z-gate preact
            float inn = acc[16 + nf][r];               // i_n (biased b_ih)
            float hnn = acc[24 + nf][r];               // h_n (biased b_hh)
            rg = 1.0f / (1.0f + __expf(-rg));
            zg = 1.0f / (1.0f + __expf(-zg));
            float nn = tanhf(inn + rg * hnn);
            float h  = memory[(size_t)slot * H_SZ + j];  // exact f32 pre-update state
            float sn = (1.0f - zg) * nn + zg * h;
            if (win) out_mem[(size_t)slot * H_SZ + j] = sn;
        }
        float hv = acc[32][r];                         // heads frag (biased)
        if (col < E_SZ)       out_emo[(size_t)row * E_SZ + col] = hv;
        else if (col == E_SZ) out_shift[row] = hv;
    }
}

// ---------------- launch ----------------
extern "C" void kernel_launch(void* const* d_in, const int* in_sizes, int n_in,
                              void* d_out, int out_size, void* d_ws, size_t ws_size,
                              hipStream_t stream)
{
    const float* h_t     = (const float*)d_in[0];
    const float* h_ctx   = (const float*)d_in[1];
    const float* sent    = (const float*)d_in[2];
    const int*   slot_ids= (const int*)  d_in[3];
    const float* memory  = (const float*)d_in[4];
    const float* W_ih    = (const float*)d_in[5];
    const float* W_hh    = (const float*)d_in[6];
    const float* b_ih    = (const float*)d_in[7];
    const float* b_hh    = (const float*)d_in[8];
    const float* W_e     = (const float*)d_in[9];
    const float* b_e     = (const float*)d_in[10];
    const float* W_s     = (const float*)d_in[11];
    const float* b_s     = (const float*)d_in[12];

    float* out       = (float*)d_out;
    float* out_emo   = out;                                    // [B,7]
    float* out_shift = out + (size_t)B_SZ * E_SZ;              // [B]
    float* out_mem   = out + (size_t)B_SZ * E_SZ + B_SZ;       // [S,H]

    int*    winner = (int*)d_ws;                               // S ints
    ushort* W2f    = (ushort*)((char*)d_ws + (size_t)S_SZ * sizeof(int));

    hipMemsetAsync(winner, 0xFF, (size_t)S_SZ * sizeof(int), stream);   // -1
    hipMemcpyAsync(out_mem, memory, (size_t)S_SZ * H_SZ * sizeof(float),
                   hipMemcpyDeviceToDevice, stream);

    pack_w2f_kernel<<<(NFR * NSTEP * 64 + 255) / 256, 256, 0, stream>>>(
        W_ih, W_hh, b_ih, b_hh, W_e, b_e, W_s, b_s, W2f);
    winner_kernel<<<B_SZ / 256, 256, 0, stream>>>(slot_ids, winner);
    fused_kernel<<<B_SZ / 64, 256, 0, stream>>>(
        h_t, h_ctx, sent, slot_ids, memory, W2f, winner, out_emo, out_shift, out_mem);
}

// Round 3
// 162.348 us; speedup vs baseline: 1.3399x; 1.3399x over previous
//
#include <hip/hip_runtime.h>
#include <hip/hip_bf16.h>

// Problem constants
#define B_SZ   16384
#define D_SZ   768
#define H_SZ   128
#define S_SZ   65536
#define E_SZ   7

// Packed GEMM geometry (logical K/N spaces; B stored frag-major, see pack kernel)
// K layout: [0,768) h_t | [768,896) s_t | [896,1664) h_ctx | 1664..1666 sent | 1667 bias(1.0) | pad->1696
// N layout: [0,256) r,z (gi+gh summed) | [256,384) i_n | [384,512) h_n | [512,519) W_e | 519 W_s | pad->528
#define NFR    33      // N fragments of 16
#define NSTEP  53      // K steps of 32: 24 (h_t) + 4 (s_t) + 24 (h_ctx) + 1 (tail)

typedef __attribute__((ext_vector_type(8))) short bf16x8;
typedef __attribute__((ext_vector_type(4))) float f32x4;

static __device__ __forceinline__ ushort f2bf(float v) {
    unsigned u = __float_as_uint(v);
    u = (u + 0x7FFFu + ((u >> 16) & 1u)) >> 16;   // RNE
    return (ushort)u;
}

static __device__ __forceinline__ bf16x8 cvt8(float4 a, float4 b) {
    bf16x8 o;
    o[0] = (short)f2bf(a.x); o[1] = (short)f2bf(a.y);
    o[2] = (short)f2bf(a.z); o[3] = (short)f2bf(a.w);
    o[4] = (short)f2bf(b.x); o[5] = (short)f2bf(b.y);
    o[6] = (short)f2bf(b.z); o[7] = (short)f2bf(b.w);
    return o;
}

// logical packed-weight value at (n, k)
static __device__ __forceinline__ float w2_value(int n, int k,
    const float* __restrict__ W_ih, const float* __restrict__ W_hh,
    const float* __restrict__ b_ih, const float* __restrict__ b_hh,
    const float* __restrict__ W_e,  const float* __restrict__ b_e,
    const float* __restrict__ W_s,  const float* __restrict__ b_s)
{
    float v = 0.0f;
    if (n < 256) {                       // r,z rows: gi + gh summed
        if (k < 768)                        v = W_ih[(size_t)n * 771 + k];
        else if (k < 896)                   v = W_hh[(size_t)n * 128 + (k - 768)];
        else if (k >= 1664 && k < 1667)     v = W_ih[(size_t)n * 771 + 768 + (k - 1664)];
        else if (k == 1667)                 v = b_ih[n] + b_hh[n];
    } else if (n < 384) {                // i_n rows (W_ih rows 256..383)
        if (k < 768)                        v = W_ih[(size_t)n * 771 + k];
        else if (k >= 1664 && k < 1667)     v = W_ih[(size_t)n * 771 + 768 + (k - 1664)];
        else if (k == 1667)                 v = b_ih[n];
    } else if (n < 512) {                // h_n rows (W_hh rows 256..383)
        int g = n - 128;
        if (k >= 768 && k < 896)            v = W_hh[(size_t)g * 128 + (k - 768)];
        else if (k == 1667)                 v = b_hh[g];
    } else if (n < 520) {                // heads: z_t = [h_t(0:768) sent(768:771) s_t(771:899) h_ctx(899:1667)]
        int e = n - 512;
        const float* Wr = (e < E_SZ) ? (W_e + (size_t)e * 1667) : W_s;
        if (k < 768)                        v = Wr[k];
        else if (k < 896)                   v = Wr[771 + (k - 768)];
        else if (k < 1664)                  v = Wr[899 + (k - 896)];
        else if (k < 1667)                  v = Wr[768 + (k - 1664)];
        else if (k == 1667)                 v = (e < E_SZ) ? b_e[e] : b_s[0];
    }
    return v;
}

// ---------------- pack W2 frag-major: W2f[(nf*NSTEP + kstep)*64 + lane][8] ----------------
__global__ __launch_bounds__(256) void pack_w2f_kernel(
    const float* __restrict__ W_ih, const float* __restrict__ W_hh,
    const float* __restrict__ b_ih, const float* __restrict__ b_hh,
    const float* __restrict__ W_e,  const float* __restrict__ b_e,
    const float* __restrict__ W_s,  const float* __restrict__ b_s,
    ushort* __restrict__ W2f)
{
    int tid = blockIdx.x * 256 + threadIdx.x;
    if (tid >= NFR * NSTEP * 64) return;
    int lane  = tid & 63;
    int kstep = (tid >> 6) % NSTEP;
    int nf    = tid / (NSTEP * 64);
    int n     = nf * 16 + (lane & 15);
    int kbase = kstep * 32 + (lane >> 4) * 8;
    ushort o[8];
#pragma unroll
    for (int j = 0; j < 8; ++j)
        o[j] = f2bf(w2_value(n, kbase + j, W_ih, W_hh, b_ih, b_hh, W_e, b_e, W_s, b_s));
    *reinterpret_cast<uint4*>(W2f + (size_t)tid * 8) = *reinterpret_cast<const uint4*>(o);
}

// ---------------- winner (last-write-wins) ----------------
__global__ __launch_bounds__(256) void winner_kernel(const int* __restrict__ slot_ids,
                                                     int* __restrict__ winner)
{
    int b = blockIdx.x * 256 + threadIdx.x;
    if (b < B_SZ) atomicMax(&winner[slot_ids[b]], b);
}

// ---------------- per-step MFMA over compile-time frag ranges ----------------
template<int LO1, int HI1, int LO2, int HI2>
static __device__ __forceinline__ void mfma_step(const ushort* __restrict__ W2f,
                                                 int kstep, int lane, bf16x8 a, f32x4* acc)
{
#pragma unroll
    for (int nf = LO1; nf < HI1; ++nf) {
        bf16x8 b = *reinterpret_cast<const bf16x8*>(
            W2f + ((size_t)(nf * NSTEP + kstep) * 64 + lane) * 8);
        acc[nf] = __builtin_amdgcn_mfma_f32_16x16x32_bf16(a, b, acc[nf], 0, 0, 0);
    }
#pragma unroll
    for (int nf = LO2; nf < HI2; ++nf) {
        bf16x8 b = *reinterpret_cast<const bf16x8*>(
            W2f + ((size_t)(nf * NSTEP + kstep) * 64 + lane) * 8);
        acc[nf] = __builtin_amdgcn_mfma_f32_16x16x32_bf16(a, b, acc[nf], 0, 0, 0);
    }
}

// ---------------- LDS reduction helpers (frag ranges compile-time) ----------------
template<int LO1, int HI1, int LO2, int HI2>
static __device__ __forceinline__ void red_store(f32x4* red, int lane, const f32x4* acc)
{
#pragma unroll
    for (int nf = LO1; nf < HI1; ++nf) red[nf * 64 + lane] = acc[nf];
#pragma unroll
    for (int nf = LO2; nf < HI2; ++nf) red[nf * 64 + lane] = acc[nf];
}

template<int LO1, int HI1, int LO2, int HI2>
static __device__ __forceinline__ void red_add(const f32x4* red, int lane, f32x4* acc)
{
#pragma unroll
    for (int nf = LO1; nf < HI1; ++nf) acc[nf] += red[nf * 64 + lane];
#pragma unroll
    for (int nf = LO2; nf < HI2; ++nf) acc[nf] += red[nf * 64 + lane];
}

// ---------------- fused GEMM + GRU + heads + scatter (K-split x4 per 16-row block) ----------------
__global__ __launch_bounds__(256, 3) void fused_kernel(
    const float* __restrict__ h_t,   const float* __restrict__ h_ctx,
    const float* __restrict__ sent,  const int* __restrict__ slot_ids,
    const float* __restrict__ memory,const ushort* __restrict__ W2f,
    const int* __restrict__ winner,
    float* __restrict__ out_emo, float* __restrict__ out_shift, float* __restrict__ out_mem)
{
    __shared__ alignas(16) f32x4 red[NFR * 64];   // 33.8 KB single reduction buffer

    const int tid  = threadIdx.x;
    const int wave = tid >> 6;
    const int lane = tid & 63;
    const int col  = lane & 15;
    const int kg   = lane >> 4;
    const int row0 = blockIdx.x * 16;
    const int rowA = row0 + col;                  // A-fragment row for this lane

    f32x4 acc[NFR];
#pragma unroll
    for (int i = 0; i < NFR; ++i) { f32x4 z = {0.f, 0.f, 0.f, 0.f}; acc[i] = z; }

    if (wave < 3) {
        // h_t K-chunk: steps wave*8 .. wave*8+7. Active frags: rz+i_n [0,24) + heads [32,33)
        const float* base = h_t + (size_t)rowA * D_SZ + kg * 8;
        const int s0 = wave * 8;
        float4 na0 = *reinterpret_cast<const float4*>(base + s0 * 32);
        float4 na1 = *reinterpret_cast<const float4*>(base + s0 * 32 + 4);
        for (int i = 0; i < 8; ++i) {
            bf16x8 a = cvt8(na0, na1);
            if (i < 7) {
                const float* p = base + (s0 + i + 1) * 32;
                na0 = *reinterpret_cast<const float4*>(p);
                na1 = *reinterpret_cast<const float4*>(p + 4);
            }
            mfma_step<0, 24, 32, 33>(W2f, s0 + i, lane, a, acc);
        }
    } else {
        // s_t gather (steps 24..27). Active: rz [0,16) + h_n+heads [24,33)
        const int slotA = slot_ids[rowA];
        const float* mbase = memory + (size_t)slotA * H_SZ + kg * 8;
#pragma unroll
        for (int i = 0; i < 4; ++i) {
            float4 v0 = *reinterpret_cast<const float4*>(mbase + i * 32);
            float4 v1 = *reinterpret_cast<const float4*>(mbase + i * 32 + 4);
            mfma_step<0, 16, 24, 33>(W2f, 24 + i, lane, cvt8(v0, v1), acc);
        }
        // h_ctx (steps 28..51). Active: heads only [32,33)
        const float* cbase = h_ctx + (size_t)rowA * D_SZ + kg * 8;
#pragma unroll 4
        for (int i = 0; i < 24; ++i) {
            float4 v0 = *reinterpret_cast<const float4*>(cbase + i * 32);
            float4 v1 = *reinterpret_cast<const float4*>(cbase + i * 32 + 4);
            mfma_step<32, 33, 33, 33>(W2f, 28 + i, lane, cvt8(v0, v1), acc);
        }
        // tail (step 52): sent(3) + bias-one + zeros. Active: all frags
        bf16x8 a;
#pragma unroll
        for (int j = 0; j < 8; ++j) {
            int kk = kg * 8 + j;
            float v = 0.0f;
            if (kk < 3)       v = sent[(size_t)rowA * 3 + kk];
            else if (kk == 3) v = 1.0f;
            a[j] = (short)f2bf(v);
        }
        mfma_step<0, 33, 33, 33>(W2f, 52, lane, a, acc);
    }

    // --- serial cross-wave reduction into wave 0 (single 33.8 KB buffer) ---
    if (wave == 1) red_store<0, 24, 32, 33>(red, lane, acc);
    __syncthreads();
    if (wave == 0) red_add<0, 24, 32, 33>(red, lane, acc);
    __syncthreads();
    if (wave == 2) red_store<0, 24, 32, 33>(red, lane, acc);
    __syncthreads();
    if (wave == 0) red_add<0, 24, 32, 33>(red, lane, acc);
    __syncthreads();
    if (wave == 3) red_store<0, 33, 33, 33>(red, lane, acc);
    __syncthreads();

    if (wave == 0) {
        red_add<0, 33, 33, 33>(red, lane, acc);
        // Epilogue: lane-local GRU + heads + winner-scatter.
        // D layout: col = lane&15, row = (lane>>4)*4 + reg
#pragma unroll
        for (int r = 0; r < 4; ++r) {
            const int row  = row0 + kg * 4 + r;
            const int slot = slot_ids[row];
            const bool win = (winner[slot] == row);
#pragma unroll
            for (int nf = 0; nf < 8; ++nf) {
                const int j = nf * 16 + col;               // hidden index 0..127
                float rg  = acc[nf][r];                    // r-gate preact (biased)
                float zg  = acc[8 + nf][r];                // z-gate preact
                float inn = acc[16 + nf][r];               // i_n (biased b_ih)
                float hnn = acc[24 + nf][r];               // h_n (biased b_hh)
                rg = 1.0f / (1.0f + __expf(-rg));
                zg = 1.0f / (1.0f + __expf(-zg));
                float nn = tanhf(inn + rg * hnn);
                float h  = memory[(size_t)slot * H_SZ + j];  // exact f32 pre-update state
                float sn = (1.0f - zg) * nn + zg * h;
                if (win) out_mem[(size_t)slot * H_SZ + j] = sn;
            }
            float hv = acc[32][r];                         // heads frag (biased)
            if (col < E_SZ)       out_emo[(size_t)row * E_SZ + col] = hv;
            else if (col == E_SZ) out_shift[row] = hv;
        }
    }
}

// ---------------- launch ----------------
extern "C" void kernel_launch(void* const* d_in, const int* in_sizes, int n_in,
                              void* d_out, int out_size, void* d_ws, size_t ws_size,
                              hipStream_t stream)
{
    const float* h_t     = (const float*)d_in[0];
    const float* h_ctx   = (const float*)d_in[1];
    const float* sent    = (const float*)d_in[2];
    const int*   slot_ids= (const int*)  d_in[3];
    const float* memory  = (const float*)d_in[4];
    const float* W_ih    = (const float*)d_in[5];
    const float* W_hh    = (const float*)d_in[6];
    const float* b_ih    = (const float*)d_in[7];
    const float* b_hh    = (const float*)d_in[8];
    const float* W_e     = (const float*)d_in[9];
    const float* b_e     = (const float*)d_in[10];
    const float* W_s     = (const float*)d_in[11];
    const float* b_s     = (const float*)d_in[12];

    float* out       = (float*)d_out;
    float* out_emo   = out;                                    // [B,7]
    float* out_shift = out + (size_t)B_SZ * E_SZ;              // [B]
    float* out_mem   = out + (size_t)B_SZ * E_SZ + B_SZ;       // [S,H]

    int*    winner = (int*)d_ws;                               // S ints
    ushort* W2f    = (ushort*)((char*)d_ws + (size_t)S_SZ * sizeof(int));

    hipMemsetAsync(winner, 0xFF, (size_t)S_SZ * sizeof(int), stream);   // -1
    hipMemcpyAsync(out_mem, memory, (size_t)S_SZ * H_SZ * sizeof(float),
                   hipMemcpyDeviceToDevice, stream);

    pack_w2f_kernel<<<(NFR * NSTEP * 64 + 255) / 256, 256, 0, stream>>>(
        W_ih, W_hh, b_ih, b_hh, W_e, b_e, W_s, b_s, W2f);
    winner_kernel<<<B_SZ / 256, 256, 0, stream>>>(slot_ids, winner);
    fused_kernel<<<B_SZ / 16, 256, 0, stream>>>(
        h_t, h_ctx, sent, slot_ids, memory, W2f, winner, out_emo, out_shift, out_mem);
}

// Round 5
// 102.770 us; speedup vs baseline: 2.1167x; 1.5797x over previous
//
#include <hip/hip_runtime.h>
#include <hip/hip_bf16.h>

// Problem constants
#define B_SZ   16384
#define D_SZ   768
#define H_SZ   128
#define S_SZ   65536
#define E_SZ   7

// Packed GEMM geometry (logical K/N spaces; B stored frag-major, see pack kernel)
// K layout: [0,768) h_t | [768,896) s_t | [896,1664) h_ctx | 1664..1666 sent | 1667 bias(1.0) | pad->1696
// N layout: [0,256) r,z (gi+gh summed) | [256,384) i_n | [384,512) h_n | [512,519) W_e | 519 W_s | pad->528
// Frag K-activity: [0,16) rz: h_t+s_t+tail | [16,24) i_n: h_t+tail | [24,32) h_n: s_t+tail | 32 heads: all
#define NFR    33      // N fragments of 16
#define NSTEP  53      // K steps of 32: 24 (h_t) + 4 (s_t) + 24 (h_ctx) + 1 (tail)

typedef __attribute__((ext_vector_type(8))) short bf16x8;
typedef __attribute__((ext_vector_type(4))) float f32x4;

static __device__ __forceinline__ ushort f2bf(float v) {
    unsigned u = __float_as_uint(v);
    u = (u + 0x7FFFu + ((u >> 16) & 1u)) >> 16;   // RNE
    return (ushort)u;
}

static __device__ __forceinline__ bf16x8 cvt8(float4 a, float4 b) {
    bf16x8 o;
    o[0] = (short)f2bf(a.x); o[1] = (short)f2bf(a.y);
    o[2] = (short)f2bf(a.z); o[3] = (short)f2bf(a.w);
    o[4] = (short)f2bf(b.x); o[5] = (short)f2bf(b.y);
    o[6] = (short)f2bf(b.z); o[7] = (short)f2bf(b.w);
    return o;
}

// logical packed-weight value at (n, k)
static __device__ __forceinline__ float w2_value(int n, int k,
    const float* __restrict__ W_ih, const float* __restrict__ W_hh,
    const float* __restrict__ b_ih, const float* __restrict__ b_hh,
    const float* __restrict__ W_e,  const float* __restrict__ b_e,
    const float* __restrict__ W_s,  const float* __restrict__ b_s)
{
    float v = 0.0f;
    if (n < 256) {                       // r,z rows: gi + gh summed
        if (k < 768)                        v = W_ih[(size_t)n * 771 + k];
        else if (k < 896)                   v = W_hh[(size_t)n * 128 + (k - 768)];
        else if (k >= 1664 && k < 1667)     v = W_ih[(size_t)n * 771 + 768 + (k - 1664)];
        else if (k == 1667)                 v = b_ih[n] + b_hh[n];
    } else if (n < 384) {                // i_n rows (W_ih rows 256..383)
        if (k < 768)                        v = W_ih[(size_t)n * 771 + k];
        else if (k >= 1664 && k < 1667)     v = W_ih[(size_t)n * 771 + 768 + (k - 1664)];
        else if (k == 1667)                 v = b_ih[n];
    } else if (n < 512) {                // h_n rows (W_hh rows 256..383)
        int g = n - 128;
        if (k >= 768 && k < 896)            v = W_hh[(size_t)g * 128 + (k - 768)];
        else if (k == 1667)                 v = b_hh[g];
    } else if (n < 520) {                // heads: z_t = [h_t(0:768) sent(768:771) s_t(771:899) h_ctx(899:1667)]
        int e = n - 512;
        const float* Wr = (e < E_SZ) ? (W_e + (size_t)e * 1667) : W_s;
        if (k < 768)                        v = Wr[k];
        else if (k < 896)                   v = Wr[771 + (k - 768)];
        else if (k < 1664)                  v = Wr[899 + (k - 896)];
        else if (k < 1667)                  v = Wr[768 + (k - 1664)];
        else if (k == 1667)                 v = (e < E_SZ) ? b_e[e] : b_s[0];
    }
    return v;
}

// ---------------- pack W2 frag-major: W2f[(nf*NSTEP + kstep)*64 + lane][8] ----------------
__global__ __launch_bounds__(256) void pack_w2f_kernel(
    const float* __restrict__ W_ih, const float* __restrict__ W_hh,
    const float* __restrict__ b_ih, const float* __restrict__ b_hh,
    const float* __restrict__ W_e,  const float* __restrict__ b_e,
    const float* __restrict__ W_s,  const float* __restrict__ b_s,
    ushort* __restrict__ W2f)
{
    int tid = blockIdx.x * 256 + threadIdx.x;
    if (tid >= NFR * NSTEP * 64) return;
    int lane  = tid & 63;
    int kstep = (tid >> 6) % NSTEP;
    int nf    = tid / (NSTEP * 64);
    int n     = nf * 16 + (lane & 15);
    int kbase = kstep * 32 + (lane >> 4) * 8;
    ushort o[8];
#pragma unroll
    for (int j = 0; j < 8; ++j)
        o[j] = f2bf(w2_value(n, kbase + j, W_ih, W_hh, b_ih, b_hh, W_e, b_e, W_s, b_s));
    *reinterpret_cast<uint4*>(W2f + (size_t)tid * 8) = *reinterpret_cast<const uint4*>(o);
}

// ---------------- winner (last-write-wins) ----------------
__global__ __launch_bounds__(256) void winner_kernel(const int* __restrict__ slot_ids,
                                                     int* __restrict__ winner)
{
    int b = blockIdx.x * 256 + threadIdx.x;
    if (b < B_SZ) atomicMax(&winner[slot_ids[b]], b);
}

// ---------------- MFMA over up to three compile-time frag ranges (acc offset LO) ----------------
template<int LO, int A1, int B1, int A2, int B2, int A3, int B3>
static __device__ __forceinline__ void mfma_rng(const ushort* __restrict__ W2f,
                                                int kstep, int lane, bf16x8 a, f32x4* acc)
{
#pragma unroll
    for (int nf = A1; nf < B1; ++nf) {
        bf16x8 b = *reinterpret_cast<const bf16x8*>(
            W2f + ((size_t)(nf * NSTEP + kstep) * 64 + lane) * 8);
        acc[nf - LO] = __builtin_amdgcn_mfma_f32_16x16x32_bf16(a, b, acc[nf - LO], 0, 0, 0);
    }
#pragma unroll
    for (int nf = A2; nf < B2; ++nf) {
        bf16x8 b = *reinterpret_cast<const bf16x8*>(
            W2f + ((size_t)(nf * NSTEP + kstep) * 64 + lane) * 8);
        acc[nf - LO] = __builtin_amdgcn_mfma_f32_16x16x32_bf16(a, b, acc[nf - LO], 0, 0, 0);
    }
#pragma unroll
    for (int nf = A3; nf < B3; ++nf) {
        bf16x8 b = *reinterpret_cast<const bf16x8*>(
            W2f + ((size_t)(nf * NSTEP + kstep) * 64 + lane) * 8);
        acc[nf - LO] = __builtin_amdgcn_mfma_f32_16x16x32_bf16(a, b, acc[nf - LO], 0, 0, 0);
    }
}

// ---------------- per-wave N-subset compute over full K ----------------
template<int LO, int HI>
static __device__ __forceinline__ void wave_compute(
    const float* __restrict__ h_t, const float* __restrict__ h_ctx,
    const float* __restrict__ sent, const float* __restrict__ memory,
    int rowA, int slotA, int kg, int lane,
    const ushort* __restrict__ W2f, f32x4* acc, f32x4* red)
{
    constexpr int HT_E  = HI < 24 ? HI : 24;   // h_t-active rz/i_n end
    constexpr int ST_E1 = HI < 16 ? HI : 16;   // s_t-active rz end
    constexpr int ST_B2 = LO > 24 ? LO : 24;   // s_t-active h_n begin
    constexpr int ST_E2 = HI < 32 ? HI : 32;   // s_t-active h_n end
    constexpr int HD_B  = HI >= 33 ? 32 : 33;  // heads frag (empty range if absent)

    // h_t steps 0..23
    {
        const float* base = h_t + (size_t)rowA * D_SZ + kg * 8;
#pragma unroll 4
        for (int s = 0; s < 24; ++s) {
            float4 v0 = *reinterpret_cast<const float4*>(base + s * 32);
            float4 v1 = *reinterpret_cast<const float4*>(base + s * 32 + 4);
            mfma_rng<LO, LO, HT_E, HD_B, 33, 33, 33>(W2f, s, lane, cvt8(v0, v1), acc);
        }
    }
    // s_t steps 24..27 (gather)
    {
        const float* mbase = memory + (size_t)slotA * H_SZ + kg * 8;
#pragma unroll
        for (int i = 0; i < 4; ++i) {
            float4 v0 = *reinterpret_cast<const float4*>(mbase + i * 32);
            float4 v1 = *reinterpret_cast<const float4*>(mbase + i * 32 + 4);
            mfma_rng<LO, LO, ST_E1, ST_B2, ST_E2, HD_B, 33>(W2f, 24 + i, lane, cvt8(v0, v1), acc);
        }
    }
    // h_ctx steps 28..51 (heads only)
    if constexpr (HI >= 33) {
        const float* cbase = h_ctx + (size_t)rowA * D_SZ + kg * 8;
#pragma unroll 4
        for (int i = 0; i < 24; ++i) {
            float4 v0 = *reinterpret_cast<const float4*>(cbase + i * 32);
            float4 v1 = *reinterpret_cast<const float4*>(cbase + i * 32 + 4);
            mfma_rng<LO, 32, 33, 33, 33, 33, 33>(W2f, 28 + i, lane, cvt8(v0, v1), acc);
        }
    }
    // tail step 52: sent(3) + bias-one + zeros -> all frags in [LO,HI)
    {
        bf16x8 a;
#pragma unroll
        for (int j = 0; j < 8; ++j) {
            int kk = kg * 8 + j;
            float v = 0.0f;
            if (kk < 3)       v = sent[(size_t)rowA * 3 + kk];
            else if (kk == 3) v = 1.0f;
            a[j] = (short)f2bf(v);
        }
        mfma_rng<LO, LO, HI, 33, 33, 33, 33>(W2f, 52, lane, a, acc);
    }
    // dump partials for the shared epilogue
#pragma unroll
    for (int nf = LO; nf < HI; ++nf) red[nf * 64 + lane] = acc[nf - LO];
}

// ---------------- fused GEMM (N-split waves) + shared GRU/heads/scatter epilogue ----------------
__global__ __launch_bounds__(256) void fused_kernel(
    const float* __restrict__ h_t,   const float* __restrict__ h_ctx,
    const float* __restrict__ sent,  const int* __restrict__ slot_ids,
    const float* __restrict__ memory,const ushort* __restrict__ W2f,
    const int* __restrict__ winner,
    float* __restrict__ out_emo, float* __restrict__ out_shift, float* __restrict__ out_mem)
{
    __shared__ alignas(16) f32x4 red[NFR * 64];   // 33.8 KB

    const int tid  = threadIdx.x;
    const int wave = tid >> 6;
    const int lane = tid & 63;
    const int row0 = blockIdx.x * 16;
    const int rowA = row0 + (lane & 15);
    const int kg   = lane >> 4;
    const int slotA = slot_ids[rowA];

    if (wave == 0) {
        f32x4 acc[7];
#pragma unroll
        for (int i = 0; i < 7; ++i) { f32x4 z = {0.f,0.f,0.f,0.f}; acc[i] = z; }
        wave_compute<0, 7>(h_t, h_ctx, sent, memory, rowA, slotA, kg, lane, W2f, acc, red);
    } else if (wave == 1) {
        f32x4 acc[7];
#pragma unroll
        for (int i = 0; i < 7; ++i) { f32x4 z = {0.f,0.f,0.f,0.f}; acc[i] = z; }
        wave_compute<7, 14>(h_t, h_ctx, sent, memory, rowA, slotA, kg, lane, W2f, acc, red);
    } else if (wave == 2) {
        f32x4 acc[7];
#pragma unroll
        for (int i = 0; i < 7; ++i) { f32x4 z = {0.f,0.f,0.f,0.f}; acc[i] = z; }
        wave_compute<14, 21>(h_t, h_ctx, sent, memory, rowA, slotA, kg, lane, W2f, acc, red);
    } else {
        f32x4 acc[12];
#pragma unroll
        for (int i = 0; i < 12; ++i) { f32x4 z = {0.f,0.f,0.f,0.f}; acc[i] = z; }
        wave_compute<21, 33>(h_t, h_ctx, sent, memory, rowA, slotA, kg, lane, W2f, acc, red);
    }

    __syncthreads();

    // Epilogue: thread -> (row = tid>>4, col = tid&15); LDS elem(nf,row,col) =
    // red[nf*64 + (row>>2)*16 + col][row&3]  (2 lanes/bank -> conflict-free)
    const int erow = tid >> 4;
    const int ecol = tid & 15;
    const int grow = row0 + erow;
    const int li   = (erow >> 2) * 16 + ecol;
    const int rsel = erow & 3;
    const int slot = slot_ids[grow];
    const bool win = (winner[slot] == grow);

#pragma unroll
    for (int q = 0; q < 8; ++q) {
        float rg  = red[q * 64 + li][rsel];
        float zg  = red[(8 + q) * 64 + li][rsel];
        float inn = red[(16 + q) * 64 + li][rsel];
        float hnn = red[(24 + q) * 64 + li][rsel];
        rg = 1.0f / (1.0f + __expf(-rg));
        zg = 1.0f / (1.0f + __expf(-zg));
        float nn = tanhf(inn + rg * hnn);
        float h  = memory[(size_t)slot * H_SZ + q * 16 + ecol];   // exact f32 pre-update state
        float sn = (1.0f - zg) * nn + zg * h;
        if (win) out_mem[(size_t)slot * H_SZ + q * 16 + ecol] = sn;
    }
    float hv = red[32 * 64 + li][rsel];
    if (ecol < E_SZ)       out_emo[(size_t)grow * E_SZ + ecol] = hv;
    else if (ecol == E_SZ) out_shift[grow] = hv;
}

// ---------------- launch ----------------
extern "C" void kernel_launch(void* const* d_in, const int* in_sizes, int n_in,
                              void* d_out, int out_size, void* d_ws, size_t ws_size,
                              hipStream_t stream)
{
    const float* h_t     = (const float*)d_in[0];
    const float* h_ctx   = (const float*)d_in[1];
    const float* sent    = (const float*)d_in[2];
    const int*   slot_ids= (const int*)  d_in[3];
    const float* memory  = (const float*)d_in[4];
    const float* W_ih    = (const float*)d_in[5];
    const float* W_hh    = (const float*)d_in[6];
    const float* b_ih    = (const float*)d_in[7];
    const float* b_hh    = (const float*)d_in[8];
    const float* W_e     = (const float*)d_in[9];
    const float* b_e     = (const float*)d_in[10];
    const float* W_s     = (const float*)d_in[11];
    const float* b_s     = (const float*)d_in[12];

    float* out       = (float*)d_out;
    float* out_emo   = out;                                    // [B,7]
    float* out_shift = out + (size_t)B_SZ * E_SZ;              // [B]
    float* out_mem   = out + (size_t)B_SZ * E_SZ + B_SZ;       // [S,H]

    int*    winner = (int*)d_ws;                               // S ints
    ushort* W2f    = (ushort*)((char*)d_ws + (size_t)S_SZ * sizeof(int));

    hipMemsetAsync(winner, 0xFF, (size_t)S_SZ * sizeof(int), stream);   // -1
    hipMemcpyAsync(out_mem, memory, (size_t)S_SZ * H_SZ * sizeof(float),
                   hipMemcpyDeviceToDevice, stream);

    pack_w2f_kernel<<<(NFR * NSTEP * 64 + 255) / 256, 256, 0, stream>>>(
        W_ih, W_hh, b_ih, b_hh, W_e, b_e, W_s, b_s, W2f);
    winner_kernel<<<B_SZ / 256, 256, 0, stream>>>(slot_ids, winner);
    fused_kernel<<<B_SZ / 16, 256, 0, stream>>>(
        h_t, h_ctx, sent, slot_ids, memory, W2f, winner, out_emo, out_shift, out_mem);
}